// Round 9
// baseline (219.470 us; speedup 1.0000x reference)
//
#include <hip/hip_runtime.h>

#define N_NODES 50000
#define E_EDGES 600000
#define IN_DIM  128
#define HID     256
#define OUT_DIM 128
#define CAP     64    // bucket capacity (deg ~ Poisson(12), max ~35)

#define NB_FILL 2344  // (E_EDGES+255)/256, 1 edge/thread (TLP on latency-bound path)
#define NB_HCVT 3125  // 50000*128/8 elems-per-thread / 256
#define NB_WCVT 384   // (65536+32768)/256

typedef __bf16 bf16x8 __attribute__((ext_vector_type(8)));
typedef float  f32x16 __attribute__((ext_vector_type(16)));
typedef unsigned short u16x8 __attribute__((ext_vector_type(8)));

__device__ __forceinline__ unsigned short f2bf(float f) {
    union { float f; unsigned int i; } v; v.f = f;
    unsigned int b = v.i;
    b += 0x7fffu + ((b >> 16) & 1u);   // RNE
    return (unsigned short)(b >> 16);
}
__device__ __forceinline__ float bf2f(unsigned short u) {
    union { unsigned int i; float f; } v; v.i = ((unsigned int)u) << 16; return v.f;
}

// ---------------------------------------------------------------------------
// Fused prep: [fill buckets, 1 edge/thread] + [h fp32->bf16, self half only]
// + [W1/W2 -> swizzled bf16]. Swizzle order (K16-step major, identical to r7):
//   w1sw flat = ((K16*2 + g)*256 + n)*8 + j,  k = K16*16 + g*8 + j
//   w2sw flat = ((K16*2 + g)*128 + n)*8 + j
// ---------------------------------------------------------------------------
__global__ void __launch_bounds__(256)
sage_prep(const int* __restrict__ src, const int* __restrict__ dst,
          int* __restrict__ counts, int* __restrict__ bucket,
          const float* __restrict__ h, unsigned short* __restrict__ ht,
          const float* __restrict__ W1, const float* __restrict__ W2,
          unsigned short* __restrict__ w1sw, unsigned short* __restrict__ w2sw) {
    int b = blockIdx.x;
    if (b < NB_FILL) {
        int e = b * 256 + threadIdx.x;
        if (e < E_EDGES) {
            int d = dst[e];
            int slot = atomicAdd(counts + d, 1);
            if (slot < CAP) bucket[(size_t)d * CAP + slot] = src[e];
        }
    } else if (b < NB_FILL + NB_HCVT) {
        int idx = (b - NB_FILL) * 256 + threadIdx.x;   // 800k x 8 elems
        int n = idx >> 4, g = idx & 15;
        const float4 v0 = *(const float4*)(h + (size_t)n * IN_DIM + g * 8);
        const float4 v1 = *(const float4*)(h + (size_t)n * IN_DIM + g * 8 + 4);
        u16x8 o;
        o[0] = f2bf(v0.x); o[1] = f2bf(v0.y); o[2] = f2bf(v0.z); o[3] = f2bf(v0.w);
        o[4] = f2bf(v1.x); o[5] = f2bf(v1.y); o[6] = f2bf(v1.z); o[7] = f2bf(v1.w);
        *(u16x8*)(ht + (size_t)n * IN_DIM + g * 8) = o;
    } else {
        int i = (b - NB_FILL - NB_HCVT) * 256 + threadIdx.x;
        if (i < 65536) {
            int j = i & 7, n = (i >> 3) & 255, k16 = i >> 11;   // k16 = K16*2+g
            int k = (k16 >> 1) * 16 + (k16 & 1) * 8 + j;
            w1sw[i] = f2bf(W1[(size_t)k * HID + n]);
        } else {
            int i2 = i - 65536;
            int j = i2 & 7, n = (i2 >> 3) & 127, k16 = i2 >> 10;
            int k = (k16 >> 1) * 16 + (k16 & 1) * 8 + j;
            w2sw[i2] = f2bf(W2[(size_t)k * OUT_DIM + n]);
        }
    }
}

// ---------------------------------------------------------------------------
// Fused gather-mean + 2-layer MLP via v_mfma_f32_32x32x16_bf16.
// Block = 256 threads = 4 waves = 64 rows (2 strips of 32).
// Phase 0: per-block neighbor gather -> mean_s LDS (8 units of (wave,lg),
//          8 nodes each, 8-deep row prefetch). Overlaps W1 chunk-0 staging.
// Layer 1: K chunked by 32 (8 chunks, 16 KB wbuf); A-frags k<128 from ht
//          (global, L1-hot), k>=128 from mean_s (LDS). Each LDS B-fragment
//          feeds 2 MFMAs (2 row strips).
// hid -> hid_s pool (overlays mean_s; extra barrier first), layer 2 K
// chunked by 64 (4 chunks).
// Layouts: A[m=lane&31][k=(lane>>5)*8+j], B[k][n=lane&31],
//   C/D col=lane&31, row=(reg&3)+8*(reg>>2)+4*(lane>>5).
// ---------------------------------------------------------------------------
__global__ void __launch_bounds__(256)
sage_mlp(const unsigned short* __restrict__ ht,
         const int* __restrict__ counts,
         const int* __restrict__ bucket,
         const unsigned short* __restrict__ w1sw,
         const unsigned short* __restrict__ w2sw,
         const float* __restrict__ b1,
         const float* __restrict__ b2,
         float* __restrict__ out) {
    __shared__ unsigned short wbuf[8192];     // 16 KB weight staging
    __shared__ unsigned short pool[16896];    // 33 KB: mean_s [64][132] then hid_s [64][264]
    unsigned short* mean_s = pool;            // stride 132
    unsigned short* hid_s  = pool;            // stride 264 (after barrier)

    const int t = threadIdx.x;
    const int nw = t >> 6;
    const int lane = t & 63;
    const int lr = lane & 31;
    const int lg = lane >> 5;
    const int base = blockIdx.x * 64;
    const int row0 = min(base + lr,      N_NODES - 1);
    const int row1 = min(base + 32 + lr, N_NODES - 1);

    // ---- Phase 0: gather neighbor means into mean_s ------------------------
    // unit (nw,lg) handles rows nw*16 + lg*8 + [0,8); 32 lanes = 4 cols each.
    #pragma unroll
    for (int mi = 0; mi < 8; ++mi) {
        int m = nw * 16 + lg * 8 + mi;
        int node = base + m;
        float a0 = 0.f, a1 = 0.f, a2 = 0.f, a3 = 0.f;
        int dg = 0;
        if (node < N_NODES) {
            dg = counts[node];
            int en = min(dg, CAP);
            const int* bk = bucket + (size_t)node * CAP;
            int e = 0;
            for (; e + 8 <= en; e += 8) {
                const int4 sA = *(const int4*)(bk + e);
                const int4 sB = *(const int4*)(bk + e + 4);
                const ushort4 v0 = *(const ushort4*)(ht + (size_t)sA.x * IN_DIM + lr * 4);
                const ushort4 v1 = *(const ushort4*)(ht + (size_t)sA.y * IN_DIM + lr * 4);
                const ushort4 v2 = *(const ushort4*)(ht + (size_t)sA.z * IN_DIM + lr * 4);
                const ushort4 v3 = *(const ushort4*)(ht + (size_t)sA.w * IN_DIM + lr * 4);
                const ushort4 v4 = *(const ushort4*)(ht + (size_t)sB.x * IN_DIM + lr * 4);
                const ushort4 v5 = *(const ushort4*)(ht + (size_t)sB.y * IN_DIM + lr * 4);
                const ushort4 v6 = *(const ushort4*)(ht + (size_t)sB.z * IN_DIM + lr * 4);
                const ushort4 v7 = *(const ushort4*)(ht + (size_t)sB.w * IN_DIM + lr * 4);
                a0 += bf2f(v0.x)+bf2f(v1.x)+bf2f(v2.x)+bf2f(v3.x)+bf2f(v4.x)+bf2f(v5.x)+bf2f(v6.x)+bf2f(v7.x);
                a1 += bf2f(v0.y)+bf2f(v1.y)+bf2f(v2.y)+bf2f(v3.y)+bf2f(v4.y)+bf2f(v5.y)+bf2f(v6.y)+bf2f(v7.y);
                a2 += bf2f(v0.z)+bf2f(v1.z)+bf2f(v2.z)+bf2f(v3.z)+bf2f(v4.z)+bf2f(v5.z)+bf2f(v6.z)+bf2f(v7.z);
                a3 += bf2f(v0.w)+bf2f(v1.w)+bf2f(v2.w)+bf2f(v3.w)+bf2f(v4.w)+bf2f(v5.w)+bf2f(v6.w)+bf2f(v7.w);
            }
            if (e + 4 <= en) {
                const int4 sA = *(const int4*)(bk + e);
                const ushort4 v0 = *(const ushort4*)(ht + (size_t)sA.x * IN_DIM + lr * 4);
                const ushort4 v1 = *(const ushort4*)(ht + (size_t)sA.y * IN_DIM + lr * 4);
                const ushort4 v2 = *(const ushort4*)(ht + (size_t)sA.z * IN_DIM + lr * 4);
                const ushort4 v3 = *(const ushort4*)(ht + (size_t)sA.w * IN_DIM + lr * 4);
                a0 += bf2f(v0.x)+bf2f(v1.x)+bf2f(v2.x)+bf2f(v3.x);
                a1 += bf2f(v0.y)+bf2f(v1.y)+bf2f(v2.y)+bf2f(v3.y);
                a2 += bf2f(v0.z)+bf2f(v1.z)+bf2f(v2.z)+bf2f(v3.z);
                a3 += bf2f(v0.w)+bf2f(v1.w)+bf2f(v2.w)+bf2f(v3.w);
                e += 4;
            }
            for (; e < en; ++e) {
                const ushort4 v = *(const ushort4*)(ht + (size_t)bk[e] * IN_DIM + lr * 4);
                a0 += bf2f(v.x); a1 += bf2f(v.y); a2 += bf2f(v.z); a3 += bf2f(v.w);
            }
        }
        float inv = 1.0f / (float)max(dg, 1);
        ushort4 o;
        o.x = f2bf(a0 * inv); o.y = f2bf(a1 * inv);
        o.z = f2bf(a2 * inv); o.w = f2bf(a3 * inv);
        *(ushort4*)(mean_s + m * 132 + lr * 4) = o;
    }

    // ---- Layer 1: hid = [self|mean] (64x256) @ W1 (256x256) ----------------
    f32x16 c1[2][2];   // [strip][nt]
    #pragma unroll
    for (int e = 0; e < 16; ++e) {
        c1[0][0][e] = 0.f; c1[0][1][e] = 0.f; c1[1][0][e] = 0.f; c1[1][1][e] = 0.f;
    }

    #pragma unroll
    for (int c = 0; c < 8; ++c) {            // K chunks of 32
        if (c) __syncthreads();              // prior chunk's wbuf reads done
        {   // stage 16 KB of w1sw (identity copy)
            const bf16x8* gsrc = (const bf16x8*)(w1sw + c * 8192);
            #pragma unroll
            for (int i = 0; i < 4; ++i) {
                int off16 = i * 256 + t;
                *(bf16x8*)(wbuf + off16 * 8) = gsrc[off16];
            }
        }
        // A-frags for this chunk (k = c*32 + ks*16 + lg*8)
        bf16x8 a0[2], a1[2];
        #pragma unroll
        for (int ks = 0; ks < 2; ++ks) {
            int koff = c * 32 + ks * 16 + lg * 8;
            if (c < 4) {   // self half from global ht (L1-hot)
                a0[ks] = *(const bf16x8*)(ht + (size_t)row0 * IN_DIM + koff);
                a1[ks] = *(const bf16x8*)(ht + (size_t)row1 * IN_DIM + koff);
            } else {       // mean half from LDS (visible: barrier at c=1..)
                a0[ks] = *(const bf16x8*)(mean_s + lr * 132 + (koff - 128));
                a1[ks] = *(const bf16x8*)(mean_s + (32 + lr) * 132 + (koff - 128));
            }
        }
        __syncthreads();                     // staged chunk visible
        #pragma unroll
        for (int ks = 0; ks < 2; ++ks) {
            #pragma unroll
            for (int nt = 0; nt < 2; ++nt) {
                int n = nw * 64 + nt * 32 + lr;
                bf16x8 b = *(const bf16x8*)(wbuf + ((ks * 2 + lg) * 256 + n) * 8);
                c1[0][nt] = __builtin_amdgcn_mfma_f32_32x32x16_bf16(a0[ks], b, c1[0][nt], 0, 0, 0);
                c1[1][nt] = __builtin_amdgcn_mfma_f32_32x32x16_bf16(a1[ks], b, c1[1][nt], 0, 0, 0);
            }
        }
    }
    __syncthreads();   // all mean_s reads + wbuf reads done (pool/wbuf reusable)

    // ---- epilogue 1: + b1 -> bf16 -> hid_s [m][col], stride 264 ------------
    #pragma unroll
    for (int nt = 0; nt < 2; ++nt) {
        int col = nw * 64 + nt * 32 + lr;
        float bias = b1[col];
        #pragma unroll
        for (int s = 0; s < 2; ++s) {
            #pragma unroll
            for (int reg = 0; reg < 16; ++reg) {
                int m = s * 32 + (reg & 3) + 8 * (reg >> 2) + 4 * lg;
                hid_s[m * 264 + col] = f2bf(c1[s][nt][reg] + bias);
            }
        }
    }
    __syncthreads();

    // ---- Layer 2: out = hid (64x256) @ W2 (256x128) ------------------------
    f32x16 c2[2];
    #pragma unroll
    for (int e = 0; e < 16; ++e) { c2[0][e] = 0.f; c2[1][e] = 0.f; }

    #pragma unroll
    for (int c = 0; c < 4; ++c) {            // K chunks of 64
        if (c) __syncthreads();
        {   // stage 16 KB of w2sw
            const bf16x8* gsrc = (const bf16x8*)(w2sw + c * 8192);
            #pragma unroll
            for (int i = 0; i < 4; ++i) {
                int off16 = i * 256 + t;
                *(bf16x8*)(wbuf + off16 * 8) = gsrc[off16];
            }
        }
        __syncthreads();
        #pragma unroll
        for (int ks = 0; ks < 4; ++ks) {
            bf16x8 b = *(const bf16x8*)(wbuf + ((ks * 2 + lg) * 128 + nw * 32 + lr) * 8);
            int koff = c * 64 + ks * 16 + lg * 8;
            bf16x8 ah0 = *(const bf16x8*)(hid_s + lr * 264 + koff);
            bf16x8 ah1 = *(const bf16x8*)(hid_s + (32 + lr) * 264 + koff);
            c2[0] = __builtin_amdgcn_mfma_f32_32x32x16_bf16(ah0, b, c2[0], 0, 0, 0);
            c2[1] = __builtin_amdgcn_mfma_f32_32x32x16_bf16(ah1, b, c2[1], 0, 0, 0);
        }
    }

    // ---- epilogue 2: + b2, relu, store fp32 --------------------------------
    {
        int col = nw * 32 + lr;
        float bias = b2[col];
        #pragma unroll
        for (int s = 0; s < 2; ++s) {
            #pragma unroll
            for (int reg = 0; reg < 16; ++reg) {
                int m = s * 32 + (reg & 3) + 8 * (reg >> 2) + 4 * lg;
                int n = base + m;
                if (n < N_NODES)
                    out[(size_t)n * OUT_DIM + col] = fmaxf(c2[s][reg] + bias, 0.0f);
            }
        }
    }
}

extern "C" void kernel_launch(void* const* d_in, const int* in_sizes, int n_in,
                              void* d_out, int out_size, void* d_ws, size_t ws_size,
                              hipStream_t stream) {
    const float* h   = (const float*)d_in[0];
    const int*   src = (const int*)d_in[1];
    const int*   dst = (const int*)d_in[2];
    const float* W1  = (const float*)d_in[3];
    const float* b1  = (const float*)d_in[4];
    const float* W2  = (const float*)d_in[5];
    const float* b2  = (const float*)d_in[6];
    float* out = (float*)d_out;

    // ws: counts int[50000] | bucket int[50000*64] | w1sw bf16[65536]
    //   | w2sw bf16[32768] | ht bf16[50000*128]   (~26 MB of 256 MiB)
    int* counts = (int*)d_ws;
    int* bucket = counts + N_NODES;
    unsigned short* w1sw = (unsigned short*)(bucket + (size_t)N_NODES * CAP);
    unsigned short* w2sw = w1sw + 65536;
    unsigned short* ht   = w2sw + 32768;   // byte 13,196,608 (16-aligned)

    hipMemsetAsync(counts, 0, N_NODES * sizeof(int), stream);

    sage_prep<<<NB_FILL + NB_HCVT + NB_WCVT, 256, 0, stream>>>(
        src, dst, counts, bucket, h, ht, W1, W2, w1sw, w2sw);

    sage_mlp<<<(N_NODES + 63) / 64, 256, 0, stream>>>(
        ht, counts, bucket, w1sw, w2sw, b1, b2, out);
}

// Round 10
// 185.525 us; speedup vs baseline: 1.1830x; 1.1830x over previous
//
#include <hip/hip_runtime.h>

#define N_NODES 50000
#define E_EDGES 600000
#define IN_DIM  128
#define HID     256
#define OUT_DIM 128
#define SH      4     // counter shards per node
#define SCAP    16    // capacity per shard (deg ~ Poisson(12) -> ~3/shard; P(>16) ~ 1e-9)

#define NB_FILL 2344  // (E_EDGES+255)/256, 1 edge/thread (max TLP on latency-bound path)
#define NB_HCVT 3125  // 50000*128 elems / 8 per thread / 256
#define NB_WCVT 384   // (65536+32768)/256

typedef __bf16 bf16x8 __attribute__((ext_vector_type(8)));
typedef float  f32x16 __attribute__((ext_vector_type(16)));
typedef unsigned short u16x8 __attribute__((ext_vector_type(8)));

__device__ __forceinline__ unsigned short f2bf(float f) {
    union { float f; unsigned int i; } v; v.f = f;
    unsigned int b = v.i;
    b += 0x7fffu + ((b >> 16) & 1u);   // RNE
    return (unsigned short)(b >> 16);
}
__device__ __forceinline__ float bf2f(unsigned short u) {
    union { unsigned int i; float f; } v; v.i = ((unsigned int)u) << 16; return v.f;
}

// ---------------------------------------------------------------------------
// Fused prep: [fill sharded buckets] + [h fp32->bf16 into ht self-half] +
// [W1/W2 -> swizzled bf16, r7 32KB-chunk layout].
//   counts[node*4 + (e&3)]; bucket ushort[node*64 + shard*16 + slot]
//   w1sw flat = (((c*4 + ks)*2 + g)*256 + n)*8 + j,  k = c*64 + ks*16 + g*8 + j
//   w2sw flat = (((c*8 + ks)*2 + g)*128 + n)*8 + j,  k = c*128 + ks*16 + g*8 + j
// ---------------------------------------------------------------------------
__global__ void __launch_bounds__(256)
sage_prep(const int* __restrict__ src, const int* __restrict__ dst,
          int* __restrict__ counts, unsigned short* __restrict__ bucket,
          const float* __restrict__ h, unsigned short* __restrict__ ht,
          const float* __restrict__ W1, const float* __restrict__ W2,
          unsigned short* __restrict__ w1sw, unsigned short* __restrict__ w2sw) {
    int b = blockIdx.x;
    if (b < NB_FILL) {
        int e = b * 256 + threadIdx.x;
        if (e < E_EDGES) {
            int d = dst[e];
            int sh = e & (SH - 1);
            int slot = atomicAdd(counts + d * SH + sh, 1);
            if (slot < SCAP)
                bucket[(size_t)d * (SH * SCAP) + sh * SCAP + slot] = (unsigned short)src[e];
        }
    } else if (b < NB_FILL + NB_HCVT) {
        int idx = (b - NB_FILL) * 256 + threadIdx.x;   // 800k x 8 elems
        int n = idx >> 4, g = idx & 15;
        const float4 v0 = *(const float4*)(h + (size_t)n * IN_DIM + g * 8);
        const float4 v1 = *(const float4*)(h + (size_t)n * IN_DIM + g * 8 + 4);
        u16x8 o;
        o[0] = f2bf(v0.x); o[1] = f2bf(v0.y); o[2] = f2bf(v0.z); o[3] = f2bf(v0.w);
        o[4] = f2bf(v1.x); o[5] = f2bf(v1.y); o[6] = f2bf(v1.z); o[7] = f2bf(v1.w);
        *(u16x8*)(ht + (size_t)n * 256 + g * 8) = o;
    } else {
        int i = (b - NB_FILL - NB_HCVT) * 256 + threadIdx.x;
        if (i < 65536) {
            int j = i & 7, n = (i >> 3) & 255, g = (i >> 11) & 1, ks = (i >> 12) & 3, c = i >> 14;
            int k = c * 64 + ks * 16 + g * 8 + j;
            w1sw[i] = f2bf(W1[(size_t)k * HID + n]);
        } else {
            int i2 = i - 65536;
            int j = i2 & 7, n = (i2 >> 3) & 127, g = (i2 >> 10) & 1, ks = (i2 >> 11) & 7, c = (i2 >> 14) & 1;
            int k = c * 128 + ks * 16 + g * 8 + j;
            w2sw[i2] = f2bf(W2[(size_t)k * OUT_DIM + n]);
        }
    }
}

// ---------------------------------------------------------------------------
// Neighbor gather + mean in bf16. 32 lanes/node (ushort4/lane), 8 nodes per
// 256-thread block. All 4 shard index-vectors (u16x8) preloaded, then row
// loads issue across shards for ILP. Writes ht[n][128:256].
// ---------------------------------------------------------------------------
__global__ void __launch_bounds__(256)
sage_gather(const int* __restrict__ counts,
            const unsigned short* __restrict__ bucket,
            unsigned short* ht) {
    int node = blockIdx.x * 8 + (threadIdx.x >> 5);
    int l = threadIdx.x & 31;
    if (node >= N_NODES) return;

    const int4 c4 = *(const int4*)(counts + node * SH);
    const int cs[4] = {c4.x, c4.y, c4.z, c4.w};
    int dg = c4.x + c4.y + c4.z + c4.w;

    const unsigned short* bk = bucket + (size_t)node * (SH * SCAP);
    // preload all shard index vectors (first 8 of each; avg fill ~3)
    u16x8 v[4];
    v[0] = *(const u16x8*)(bk);
    v[1] = *(const u16x8*)(bk + 16);
    v[2] = *(const u16x8*)(bk + 32);
    v[3] = *(const u16x8*)(bk + 48);

    float a0 = 0.f, a1 = 0.f, a2 = 0.f, a3 = 0.f;
    #pragma unroll
    for (int s = 0; s < 4; ++s) {
        int en = min(cs[s], SCAP);
        #pragma unroll
        for (int u = 0; u < 8; ++u) {
            if (u < en) {
                const ushort4 r = *(const ushort4*)(ht + (size_t)v[s][u] * 256 + l * 4);
                a0 += bf2f(r.x); a1 += bf2f(r.y); a2 += bf2f(r.z); a3 += bf2f(r.w);
            }
        }
        if (en > 8) {   // rare tail (P(shard>8) ~ 0.004)
            const u16x8 v2 = *(const u16x8*)(bk + s * SCAP + 8);
            #pragma unroll
            for (int u = 0; u < 8; ++u) {
                if (u + 8 < en) {
                    const ushort4 r = *(const ushort4*)(ht + (size_t)v2[u] * 256 + l * 4);
                    a0 += bf2f(r.x); a1 += bf2f(r.y); a2 += bf2f(r.z); a3 += bf2f(r.w);
                }
            }
        }
    }
    float inv = 1.0f / (float)max(dg, 1);
    ushort4 o;
    o.x = f2bf(a0 * inv); o.y = f2bf(a1 * inv);
    o.z = f2bf(a2 * inv); o.w = f2bf(a3 * inv);
    *(ushort4*)(ht + (size_t)node * 256 + 128 + l * 4) = o;
}

// ---------------------------------------------------------------------------
// Fused 2-layer MLP via v_mfma_f32_32x32x16_bf16 (identical to round 7).
// Block = 256 threads = 4 waves = 64 rows (2 strips of 32); each LDS
// B-fragment feeds 2 MFMAs. W1 staged 4 x 32KB, W2 2 x 32KB.
// ---------------------------------------------------------------------------
__global__ void __launch_bounds__(256)
sage_mlp(const unsigned short* ht,            // aliases out!
         const unsigned short* __restrict__ w1sw,
         const unsigned short* __restrict__ w2sw,
         const float* __restrict__ b1,
         const float* __restrict__ b2,
         float* out) {
    __shared__ unsigned short wbuf[16384];      // 32 KB weight staging
    __shared__ unsigned short hid_s[64][264];   // 33.8 KB hidden tile

    const int t = threadIdx.x;
    const int nw = t >> 6;
    const int lane = t & 63;
    const int lr = lane & 31;
    const int lg = lane >> 5;
    const int base = blockIdx.x * 64;
    const int row0 = min(base + lr,      N_NODES - 1);
    const int row1 = min(base + 32 + lr, N_NODES - 1);

    f32x16 c1[2][2];
    #pragma unroll
    for (int e = 0; e < 16; ++e) {
        c1[0][0][e] = 0.f; c1[0][1][e] = 0.f; c1[1][0][e] = 0.f; c1[1][1][e] = 0.f;
    }

    #pragma unroll
    for (int c = 0; c < 4; ++c) {
        if (c) __syncthreads();
        {
            const bf16x8* gsrc = (const bf16x8*)(w1sw + c * 16384);
            #pragma unroll
            for (int i = 0; i < 8; ++i) {
                int off16 = i * 256 + t;
                *(bf16x8*)(wbuf + off16 * 8) = gsrc[off16];
            }
        }
        bf16x8 a0[4], a1[4];
        #pragma unroll
        for (int ks = 0; ks < 4; ++ks) {
            int koff = (c * 4 + ks) * 16 + lg * 8;
            a0[ks] = *(const bf16x8*)(ht + (size_t)row0 * 256 + koff);
            a1[ks] = *(const bf16x8*)(ht + (size_t)row1 * 256 + koff);
        }
        __syncthreads();
        #pragma unroll
        for (int ks = 0; ks < 4; ++ks) {
            #pragma unroll
            for (int nt = 0; nt < 2; ++nt) {
                int n = nw * 64 + nt * 32 + lr;
                bf16x8 b = *(const bf16x8*)(wbuf + (((ks * 2 + lg) * 256) + n) * 8);
                c1[0][nt] = __builtin_amdgcn_mfma_f32_32x32x16_bf16(a0[ks], b, c1[0][nt], 0, 0, 0);
                c1[1][nt] = __builtin_amdgcn_mfma_f32_32x32x16_bf16(a1[ks], b, c1[1][nt], 0, 0, 0);
            }
        }
    }

    #pragma unroll
    for (int nt = 0; nt < 2; ++nt) {
        int col = nw * 64 + nt * 32 + lr;
        float bias = b1[col];
        #pragma unroll
        for (int s = 0; s < 2; ++s) {
            #pragma unroll
            for (int reg = 0; reg < 16; ++reg) {
                int m = s * 32 + (reg & 3) + 8 * (reg >> 2) + 4 * lg;
                hid_s[m][col] = f2bf(c1[s][nt][reg] + bias);
            }
        }
    }
    __syncthreads();

    f32x16 c2[2];
    #pragma unroll
    for (int e = 0; e < 16; ++e) { c2[0][e] = 0.f; c2[1][e] = 0.f; }

    #pragma unroll
    for (int c = 0; c < 2; ++c) {
        if (c) __syncthreads();
        {
            const bf16x8* gsrc = (const bf16x8*)(w2sw + c * 16384);
            #pragma unroll
            for (int i = 0; i < 8; ++i) {
                int off16 = i * 256 + t;
                *(bf16x8*)(wbuf + off16 * 8) = gsrc[off16];
            }
        }
        __syncthreads();
        #pragma unroll
        for (int ks = 0; ks < 8; ++ks) {
            bf16x8 b = *(const bf16x8*)(wbuf + ((ks * 2 + lg) * 128 + nw * 32 + lr) * 8);
            int koff = c * 128 + ks * 16 + lg * 8;
            bf16x8 ah0 = *(const bf16x8*)(&hid_s[lr][koff]);
            bf16x8 ah1 = *(const bf16x8*)(&hid_s[32 + lr][koff]);
            c2[0] = __builtin_amdgcn_mfma_f32_32x32x16_bf16(ah0, b, c2[0], 0, 0, 0);
            c2[1] = __builtin_amdgcn_mfma_f32_32x32x16_bf16(ah1, b, c2[1], 0, 0, 0);
        }
    }

    {
        int col = nw * 32 + lr;
        float bias = b2[col];
        #pragma unroll
        for (int s = 0; s < 2; ++s) {
            #pragma unroll
            for (int reg = 0; reg < 16; ++reg) {
                int m = s * 32 + (reg & 3) + 8 * (reg >> 2) + 4 * lg;
                int n = base + m;
                if (n < N_NODES)
                    out[(size_t)n * OUT_DIM + col] = fmaxf(c2[s][reg] + bias, 0.0f);
            }
        }
    }
}

extern "C" void kernel_launch(void* const* d_in, const int* in_sizes, int n_in,
                              void* d_out, int out_size, void* d_ws, size_t ws_size,
                              hipStream_t stream) {
    const float* h   = (const float*)d_in[0];
    const int*   src = (const int*)d_in[1];
    const int*   dst = (const int*)d_in[2];
    const float* W1  = (const float*)d_in[3];
    const float* b1  = (const float*)d_in[4];
    const float* W2  = (const float*)d_in[5];
    const float* b2  = (const float*)d_in[6];
    float* out = (float*)d_out;

    // ht (bf16 [50000][256] = 25.6 MB) lives in d_out; overwritten by fp32 out.
    unsigned short* ht = (unsigned short*)d_out;

    // ws: counts int[50000*4] (800 KB) | bucket ushort[50000*64] (6.4 MB)
    //   | w1sw bf16[65536] | w2sw bf16[32768]
    int* counts = (int*)d_ws;
    unsigned short* bucket = (unsigned short*)(counts + N_NODES * SH);      // byte 800,000
    unsigned short* w1sw = bucket + (size_t)N_NODES * (SH * SCAP);          // byte 7,200,000
    unsigned short* w2sw = w1sw + 65536;

    hipMemsetAsync(counts, 0, N_NODES * SH * sizeof(int), stream);

    sage_prep<<<NB_FILL + NB_HCVT + NB_WCVT, 256, 0, stream>>>(
        src, dst, counts, bucket, h, ht, W1, W2, w1sw, w2sw);

    sage_gather<<<(N_NODES + 7) / 8, 256, 0, stream>>>(counts, bucket, ht);

    sage_mlp<<<(N_NODES + 63) / 64, 256, 0, stream>>>(ht, w1sw, w2sw, b1, b2, out);
}

// Round 11
// 184.796 us; speedup vs baseline: 1.1876x; 1.0039x over previous
//
#include <hip/hip_runtime.h>

#define N_NODES 50000
#define E_EDGES 600000
#define IN_DIM  128
#define HID     256
#define OUT_DIM 128
#define CAP     64    // bucket capacity (deg ~ Poisson(12), max ~35)

#define NB_FILL 2344  // (E_EDGES+255)/256
#define NB_HCVT 6250  // (N_NODES*32+255)/256
#define NB_WCVT 384   // (65536+32768)/256

typedef __bf16 bf16x8 __attribute__((ext_vector_type(8)));
typedef float  f32x16 __attribute__((ext_vector_type(16)));

__device__ __forceinline__ unsigned short f2bf(float f) {
    union { float f; unsigned int i; } v; v.f = f;
    unsigned int b = v.i;
    b += 0x7fffu + ((b >> 16) & 1u);   // RNE
    return (unsigned short)(b >> 16);
}
__device__ __forceinline__ float bf2f(unsigned short u) {
    union { unsigned int i; float f; } v; v.i = ((unsigned int)u) << 16; return v.f;
}

// ---------------------------------------------------------------------------
// Fused prep: [fill buckets] + [h fp32->bf16] + [W1/W2 -> swizzled bf16].
// 1 edge/thread fill (max TLP on the latency-bound atomic path — r8's
// 4-edge batching regressed). Int bucket (r10's ushort+shards was neutral).
//   w1sw flat = (((c*4 + ks)*2 + g)*256 + n)*8 + j,  k = c*64 + ks*16 + g*8 + j
//   w2sw flat = (((c*8 + ks)*2 + g)*128 + n)*8 + j,  k = c*128 + ks*16 + g*8 + j
// ---------------------------------------------------------------------------
__global__ void __launch_bounds__(256)
sage_prep(const int* __restrict__ src, const int* __restrict__ dst,
          int* __restrict__ counts, int* __restrict__ bucket,
          const float* __restrict__ h, unsigned short* __restrict__ ht,
          const float* __restrict__ W1, const float* __restrict__ W2,
          unsigned short* __restrict__ w1sw, unsigned short* __restrict__ w2sw) {
    int b = blockIdx.x;
    if (b < NB_FILL) {
        int e = b * 256 + threadIdx.x;
        if (e < E_EDGES) {
            int d = dst[e];
            int slot = atomicAdd(counts + d, 1);
            if (slot < CAP) bucket[(size_t)d * CAP + slot] = src[e];
        }
    } else if (b < NB_FILL + NB_HCVT) {
        int idx = (b - NB_FILL) * 256 + threadIdx.x;
        if (idx < N_NODES * 32) {
            int n = idx >> 5, g = idx & 31;
            const float4 v = *(const float4*)(h + (size_t)n * IN_DIM + g * 4);
            ushort4 o;
            o.x = f2bf(v.x); o.y = f2bf(v.y); o.z = f2bf(v.z); o.w = f2bf(v.w);
            *(ushort4*)(ht + (size_t)n * 256 + g * 4) = o;
        }
    } else {
        int i = (b - NB_FILL - NB_HCVT) * 256 + threadIdx.x;
        if (i < 65536) {
            int j = i & 7, n = (i >> 3) & 255, g = (i >> 11) & 1, ks = (i >> 12) & 3, c = i >> 14;
            int k = c * 64 + ks * 16 + g * 8 + j;
            w1sw[i] = f2bf(W1[(size_t)k * HID + n]);
        } else {
            int i2 = i - 65536;
            int j = i2 & 7, n = (i2 >> 3) & 127, g = (i2 >> 10) & 1, ks = (i2 >> 11) & 7, c = (i2 >> 14) & 1;
            int k = c * 128 + ks * 16 + g * 8 + j;
            w2sw[i2] = f2bf(W2[(size_t)k * OUT_DIM + n]);
        }
    }
}

// ---------------------------------------------------------------------------
// Neighbor gather + mean in bf16. 32 lanes/node (ushort4/lane), 8 nodes per
// block, int4 index prefetch (4 row loads in flight). Writes ht[n][128:256].
// ---------------------------------------------------------------------------
__global__ void __launch_bounds__(256)
sage_gather(const int* __restrict__ counts,
            const int* __restrict__ bucket,
            unsigned short* ht) {
    int node = blockIdx.x * 8 + (threadIdx.x >> 5);
    int l = threadIdx.x & 31;
    if (node >= N_NODES) return;

    int dg = counts[node];
    int entries = min(dg, CAP);
    const int* bk = bucket + (size_t)node * CAP;

    float a0 = 0.f, a1 = 0.f, a2 = 0.f, a3 = 0.f;
    int e = 0;
    for (; e + 4 <= entries; e += 4) {
        const int4 s = *(const int4*)(bk + e);
        const ushort4 v0 = *(const ushort4*)(ht + (size_t)s.x * 256 + l * 4);
        const ushort4 v1 = *(const ushort4*)(ht + (size_t)s.y * 256 + l * 4);
        const ushort4 v2 = *(const ushort4*)(ht + (size_t)s.z * 256 + l * 4);
        const ushort4 v3 = *(const ushort4*)(ht + (size_t)s.w * 256 + l * 4);
        a0 += bf2f(v0.x) + bf2f(v1.x) + bf2f(v2.x) + bf2f(v3.x);
        a1 += bf2f(v0.y) + bf2f(v1.y) + bf2f(v2.y) + bf2f(v3.y);
        a2 += bf2f(v0.z) + bf2f(v1.z) + bf2f(v2.z) + bf2f(v3.z);
        a3 += bf2f(v0.w) + bf2f(v1.w) + bf2f(v2.w) + bf2f(v3.w);
    }
    for (; e < entries; ++e) {
        const ushort4 v = *(const ushort4*)(ht + (size_t)bk[e] * 256 + l * 4);
        a0 += bf2f(v.x); a1 += bf2f(v.y); a2 += bf2f(v.z); a3 += bf2f(v.w);
    }
    float inv = 1.0f / (float)max(dg, 1);
    ushort4 o;
    o.x = f2bf(a0 * inv); o.y = f2bf(a1 * inv);
    o.z = f2bf(a2 * inv); o.w = f2bf(a3 * inv);
    *(ushort4*)(ht + (size_t)node * 256 + 128 + l * 4) = o;
}

// ---------------------------------------------------------------------------
// Fused 2-layer MLP via v_mfma_f32_32x32x16_bf16, LDS-staged weights.
// Block = 256 threads = 4 waves = 64 rows (2 strips of 32).
// Wave nw owns a 64-col slice of layer 1 and a 32-col slice of layer 2, and
// computes BOTH row strips -> each LDS B-fragment feeds 2 MFMAs.
// W1 staged 4 x 32KB, W2 2 x 32KB (identity copy from pre-swizzled layout).
// hid (64x256 bf16) in LDS, 264-short stride.
// Layouts: A[m=lane&31][k=(lane>>5)*8+j], B[k][n=lane&31],
//   C/D col=lane&31, row=(reg&3)+8*(reg>>2)+4*(lane>>5).
// out (fp32) overwrites ht rows: safe, all ht reads precede stores in-block,
// blocks touch only their own rows.
// ---------------------------------------------------------------------------
__global__ void __launch_bounds__(256)
sage_mlp(const unsigned short* ht,            // aliases out!
         const unsigned short* __restrict__ w1sw,
         const unsigned short* __restrict__ w2sw,
         const float* __restrict__ b1,
         const float* __restrict__ b2,
         float* out) {
    __shared__ unsigned short wbuf[16384];      // 32 KB weight staging
    __shared__ unsigned short hid_s[64][264];   // 33.8 KB hidden tile

    const int t = threadIdx.x;
    const int nw = t >> 6;
    const int lane = t & 63;
    const int lr = lane & 31;
    const int lg = lane >> 5;
    const int base = blockIdx.x * 64;
    const int row0 = min(base + lr,      N_NODES - 1);
    const int row1 = min(base + 32 + lr, N_NODES - 1);

    f32x16 c1[2][2];
    #pragma unroll
    for (int e = 0; e < 16; ++e) {
        c1[0][0][e] = 0.f; c1[0][1][e] = 0.f; c1[1][0][e] = 0.f; c1[1][1][e] = 0.f;
    }

    #pragma unroll
    for (int c = 0; c < 4; ++c) {
        if (c) __syncthreads();
        {
            const bf16x8* gsrc = (const bf16x8*)(w1sw + c * 16384);
            #pragma unroll
            for (int i = 0; i < 8; ++i) {
                int off16 = i * 256 + t;
                *(bf16x8*)(wbuf + off16 * 8) = gsrc[off16];
            }
        }
        bf16x8 a0[4], a1[4];
        #pragma unroll
        for (int ks = 0; ks < 4; ++ks) {
            int koff = (c * 4 + ks) * 16 + lg * 8;
            a0[ks] = *(const bf16x8*)(ht + (size_t)row0 * 256 + koff);
            a1[ks] = *(const bf16x8*)(ht + (size_t)row1 * 256 + koff);
        }
        __syncthreads();
        #pragma unroll
        for (int ks = 0; ks < 4; ++ks) {
            #pragma unroll
            for (int nt = 0; nt < 2; ++nt) {
                int n = nw * 64 + nt * 32 + lr;
                bf16x8 b = *(const bf16x8*)(wbuf + (((ks * 2 + lg) * 256) + n) * 8);
                c1[0][nt] = __builtin_amdgcn_mfma_f32_32x32x16_bf16(a0[ks], b, c1[0][nt], 0, 0, 0);
                c1[1][nt] = __builtin_amdgcn_mfma_f32_32x32x16_bf16(a1[ks], b, c1[1][nt], 0, 0, 0);
            }
        }
    }

    #pragma unroll
    for (int nt = 0; nt < 2; ++nt) {
        int col = nw * 64 + nt * 32 + lr;
        float bias = b1[col];
        #pragma unroll
        for (int s = 0; s < 2; ++s) {
            #pragma unroll
            for (int reg = 0; reg < 16; ++reg) {
                int m = s * 32 + (reg & 3) + 8 * (reg >> 2) + 4 * lg;
                hid_s[m][col] = f2bf(c1[s][nt][reg] + bias);
            }
        }
    }
    __syncthreads();

    f32x16 c2[2];
    #pragma unroll
    for (int e = 0; e < 16; ++e) { c2[0][e] = 0.f; c2[1][e] = 0.f; }

    #pragma unroll
    for (int c = 0; c < 2; ++c) {
        if (c) __syncthreads();
        {
            const bf16x8* gsrc = (const bf16x8*)(w2sw + c * 16384);
            #pragma unroll
            for (int i = 0; i < 8; ++i) {
                int off16 = i * 256 + t;
                *(bf16x8*)(wbuf + off16 * 8) = gsrc[off16];
            }
        }
        __syncthreads();
        #pragma unroll
        for (int ks = 0; ks < 8; ++ks) {
            bf16x8 b = *(const bf16x8*)(wbuf + ((ks * 2 + lg) * 128 + nw * 32 + lr) * 8);
            int koff = c * 128 + ks * 16 + lg * 8;
            bf16x8 ah0 = *(const bf16x8*)(&hid_s[lr][koff]);
            bf16x8 ah1 = *(const bf16x8*)(&hid_s[32 + lr][koff]);
            c2[0] = __builtin_amdgcn_mfma_f32_32x32x16_bf16(ah0, b, c2[0], 0, 0, 0);
            c2[1] = __builtin_amdgcn_mfma_f32_32x32x16_bf16(ah1, b, c2[1], 0, 0, 0);
        }
    }

    {
        int col = nw * 32 + lr;
        float bias = b2[col];
        #pragma unroll
        for (int s = 0; s < 2; ++s) {
            #pragma unroll
            for (int reg = 0; reg < 16; ++reg) {
                int m = s * 32 + (reg & 3) + 8 * (reg >> 2) + 4 * lg;
                int n = base + m;
                if (n < N_NODES)
                    out[(size_t)n * OUT_DIM + col] = fmaxf(c2[s][reg] + bias, 0.0f);
            }
        }
    }
}

extern "C" void kernel_launch(void* const* d_in, const int* in_sizes, int n_in,
                              void* d_out, int out_size, void* d_ws, size_t ws_size,
                              hipStream_t stream) {
    const float* h   = (const float*)d_in[0];
    const int*   src = (const int*)d_in[1];
    const int*   dst = (const int*)d_in[2];
    const float* W1  = (const float*)d_in[3];
    const float* b1  = (const float*)d_in[4];
    const float* W2  = (const float*)d_in[5];
    const float* b2  = (const float*)d_in[6];
    float* out = (float*)d_out;

    // ht (bf16 [50000][256] = 25.6 MB) lives in d_out; overwritten by fp32 out.
    unsigned short* ht = (unsigned short*)d_out;

    // ws: counts int[50000] | bucket int[50000*64] | w1sw bf16[65536] | w2sw bf16[32768]
    int* counts = (int*)d_ws;
    int* bucket = counts + N_NODES;
    unsigned short* w1sw = (unsigned short*)(bucket + (size_t)N_NODES * CAP);
    unsigned short* w2sw = w1sw + 65536;

    hipMemsetAsync(counts, 0, N_NODES * sizeof(int), stream);

    sage_prep<<<NB_FILL + NB_HCVT + NB_WCVT, 256, 0, stream>>>(
        src, dst, counts, bucket, h, ht, W1, W2, w1sw, w2sw);

    sage_gather<<<(N_NODES + 7) / 8, 256, 0, stream>>>(counts, bucket, ht);

    sage_mlp<<<(N_NODES + 63) / 64, 256, 0, stream>>>(ht, w1sw, w2sw, b1, b2, out);
}